// Round 4
// baseline (33884.250 us; speedup 1.0000x reference)
//
#include <hip/hip_runtime.h>
#include <math.h>

#define T_ 100
#define B_ 64
#define S_ 128
#define E_ 512
#define H_ 1024
#define C_ 512
#define V_ 32000
#define TS_ 99            // T-1 steps
#define R_ (TS_ * B_)     // 6336 rows
#define MP_ 6400          // rows padded to multiple of 128 for MFMA
#define NT2 250           // vocab n-tiles of 128
#define NBLK 64           // persistent-kernel grid size

typedef unsigned short ushort_t;
typedef __attribute__((ext_vector_type(8))) short short8;
typedef __attribute__((ext_vector_type(4))) float f32x4;

__device__ __forceinline__ float sigm_(float x) { return 1.0f / (1.0f + __expf(-x)); }
__device__ __forceinline__ float tanh_(float x) { float e = __expf(2.0f * x); return 1.0f - 2.0f / (e + 1.0f); }
__device__ __forceinline__ ushort_t f2bf(float f) {
    unsigned u = __float_as_uint(f);
    unsigned r = (u + 0x7FFF + ((u >> 16) & 1)) >> 16;
    return (ushort_t)r;
}
__device__ __forceinline__ float bf2f(ushort_t u) { return __uint_as_float(((unsigned)u) << 16); }

__device__ __forceinline__ float wred(float v) {
    #pragma unroll
    for (int o = 32; o; o >>= 1) v += __shfl_down(v, o);
    return v;
}
__device__ __forceinline__ float wmax(float v) {
    #pragma unroll
    for (int o = 32; o; o >>= 1) v = fmaxf(v, __shfl_down(v, o));
    return v;
}

// Grid barrier with NO cache-maintenance ops: all communicated data goes
// through sc1 (agent-scope relaxed atomic) stores to virgin ring addresses,
// so no fence/invalidate is needed. __syncthreads drains each wave's vmcnt
// (compiler emits s_waitcnt vmcnt(0) before s_barrier), so all sc1 stores
// of this block are globally visible before the arrival add.
__device__ __forceinline__ void gbar(int* cnt, int* gen, int k) {
    __syncthreads();
    if (threadIdx.x == 0) {
        asm volatile("" ::: "memory");
        __builtin_amdgcn_s_waitcnt(0);
        asm volatile("" ::: "memory");
        int v = __hip_atomic_fetch_add(cnt, 1, __ATOMIC_RELAXED, __HIP_MEMORY_SCOPE_AGENT);
        if (v == k * NBLK + (NBLK - 1)) {
            __hip_atomic_store(gen, k + 1, __ATOMIC_RELAXED, __HIP_MEMORY_SCOPE_AGENT);
        } else {
            while (__hip_atomic_load(gen, __ATOMIC_RELAXED, __HIP_MEMORY_SCOPE_AGENT) < k + 1)
                __builtin_amdgcn_s_sleep(1);
        }
    }
    __syncthreads();
}

// ---------------------------------------------------------------------------
// Fused GRU phase. 64 blocks, block owns 16 j (48 packed rows).
// Wp packed [3072][1536] bf16: row c=3*jj+g = [Wih[g*1024+jj][0:512] | Whh[g*1024+jj][0:1024]].
// Outputs h (bf16) via sc1 stores into a virgin ring slot.
// ---------------------------------------------------------------------------
__device__ __forceinline__ void gru_phase(
    int tid, int c0,
    const ushort_t* __restrict__ ax,   // [64][512] bf16 (virgin ring or precomputed)
    const ushort_t* __restrict__ ah,   // [64][1024] bf16 (virgin ring)
    const ushort_t* __restrict__ Wp,
    const float* __restrict__ bi, const float* __restrict__ bh,
    const ushort_t* __restrict__ hpbf, // [64][1024] bf16 prev h
    ushort_t* __restrict__ hout,       // [64][1024] bf16 ring slot (sc1 stores)
    float* __restrict__ sm)            // 12288 floats LDS
{
    const int w = tid >> 6, lane = tid & 63, quad = lane >> 4, l16 = lane & 15;
    f32x4 accX[12] = {};
    f32x4 accH[12] = {};
    const int kc0 = w * 12;   // 48 kc slices: kc<16 -> x (K=512), kc>=16 -> h (K=1024)
    #pragma unroll
    for (int i = 0; i < 12; ++i) {
        const int kc = kc0 + i;
        const int kw = kc * 32 + quad * 8;
        short8 bfr[3];
        #pragma unroll
        for (int ct = 0; ct < 3; ++ct)
            bfr[ct] = *(const short8*)(Wp + (size_t)(c0 + ct * 16 + l16) * 1536 + kw);
        short8 af[4];
        if (kc < 16) {
            #pragma unroll
            for (int mt = 0; mt < 4; ++mt)
                af[mt] = *(const short8*)(ax + (size_t)(mt * 16 + l16) * 512 + kw);
            #pragma unroll
            for (int mt = 0; mt < 4; ++mt)
                #pragma unroll
                for (int ct = 0; ct < 3; ++ct)
                    accX[mt * 3 + ct] = __builtin_amdgcn_mfma_f32_16x16x32_bf16(af[mt], bfr[ct], accX[mt * 3 + ct], 0, 0, 0);
        } else {
            const int ko = (kc - 16) * 32 + quad * 8;
            #pragma unroll
            for (int mt = 0; mt < 4; ++mt)
                af[mt] = *(const short8*)(ah + (size_t)(mt * 16 + l16) * 1024 + ko);
            #pragma unroll
            for (int mt = 0; mt < 4; ++mt)
                #pragma unroll
                for (int ct = 0; ct < 3; ++ct)
                    accH[mt * 3 + ct] = __builtin_amdgcn_mfma_f32_16x16x32_bf16(af[mt], bfr[ct], accH[mt * 3 + ct], 0, 0, 0);
        }
    }
    // LDS reduce round 1: X partials
    #pragma unroll
    for (int p = 0; p < 12; ++p)
        #pragma unroll
        for (int r = 0; r < 4; ++r)
            sm[w * 3072 + p * 256 + (quad * 4 + r) * 16 + l16] = accX[p][r];
    __syncthreads();
    float Xg[2][2][3], Hg[2][2][3];
    #pragma unroll
    for (int q = 0; q < 2; ++q) {
        int o = q * 256 + tid, b = o >> 3, jp = o & 7;
        int mt3 = (b >> 4) * 3, e0 = (b & 15) * 16;
        #pragma unroll
        for (int jj = 0; jj < 2; ++jj)
            #pragma unroll
            for (int g = 0; g < 3; ++g) {
                int c = (jp * 2 + jj) * 3 + g;
                int p = mt3 + (c >> 4), e = e0 + (c & 15);
                Xg[q][jj][g] = sm[p * 256 + e] + sm[3072 + p * 256 + e]
                             + sm[6144 + p * 256 + e] + sm[9216 + p * 256 + e];
            }
    }
    __syncthreads();
    // LDS reduce round 2: H partials
    #pragma unroll
    for (int p = 0; p < 12; ++p)
        #pragma unroll
        for (int r = 0; r < 4; ++r)
            sm[w * 3072 + p * 256 + (quad * 4 + r) * 16 + l16] = accH[p][r];
    __syncthreads();
    #pragma unroll
    for (int q = 0; q < 2; ++q) {
        int o = q * 256 + tid, b = o >> 3, jp = o & 7;
        int mt3 = (b >> 4) * 3, e0 = (b & 15) * 16;
        #pragma unroll
        for (int jj = 0; jj < 2; ++jj)
            #pragma unroll
            for (int g = 0; g < 3; ++g) {
                int c = (jp * 2 + jj) * 3 + g;
                int p = mt3 + (c >> 4), e = e0 + (c & 15);
                Hg[q][jj][g] = sm[p * 256 + e] + sm[3072 + p * 256 + e]
                             + sm[6144 + p * 256 + e] + sm[9216 + p * 256 + e];
            }
    }
    const int j0 = c0 / 3;
    #pragma unroll
    for (int q = 0; q < 2; ++q) {
        int o = q * 256 + tid, b = o >> 3, jp = o & 7;
        unsigned pack = 0;
        #pragma unroll
        for (int jj = 0; jj < 2; ++jj) {
            int j = j0 + jp * 2 + jj;
            float r = sigm_(Xg[q][jj][0] + Hg[q][jj][0] + bi[j] + bh[j]);
            float z = sigm_(Xg[q][jj][1] + Hg[q][jj][1] + bi[1024 + j] + bh[1024 + j]);
            float n = tanh_(Xg[q][jj][2] + bi[2048 + j] + r * (Hg[q][jj][2] + bh[2048 + j]));
            float hp = bf2f(hpbf[(size_t)b * 1024 + j]);
            float h = (1.0f - z) * n + z * hp;
            pack |= ((unsigned)f2bf(h)) << (16 * jj);
        }
        __hip_atomic_store((unsigned*)(hout + (size_t)b * 1024) + (j0 >> 1) + jp, pack,
                           __ATOMIC_RELAXED, __HIP_MEMORY_SCOPE_AGENT);
    }
}

// ---------------------------------------------------------------------------
// Persistent decode loop: 64 blocks x 256 threads, 3 phases + 3 barriers/step.
// ---------------------------------------------------------------------------
__global__ __launch_bounds__(256, 1) void decode_persist(
    const ushort_t* __restrict__ xembbf,   // [R_][512]
    const ushort_t* __restrict__ ctxpbf,   // [S*B][512]
    const float*    __restrict__ ctxf,     // [S*B][512] fp32 input
    const ushort_t* __restrict__ Wp0,
    const ushort_t* __restrict__ Wp1,
    const ushort_t* __restrict__ Wh2cT,    // [1024 k][512 c] bf16 transposed
    const float* __restrict__ bi0, const float* __restrict__ bh0,
    const float* __restrict__ bi1, const float* __restrict__ bh1,
    const float* __restrict__ wmlp,
    ushort_t* __restrict__ h1ring,         // [99][64][1024]
    ushort_t* __restrict__ zring,          // [99][64][512]
    ushort_t* __restrict__ h2ring,         // [101 slots][64][1024]; slot0 = zeros
    int* cnt, int* gen)
{
    __shared__ float sm[12288];   // 48 KB, reused by all phases
    const int bid = blockIdx.x, tid = threadIdx.x;
    const int w = tid >> 6, lane = tid & 63;
    int bk = 0;
    for (int t = 0; t < TS_; ++t) {
        const ushort_t* h2prev = h2ring + (size_t)t * 65536;
        ushort_t* h1slot = h1ring + (size_t)t * 65536;
        ushort_t* zslot  = zring + (size_t)t * 32768;
        // ---- P1: GRU0 -> h1 ----
        gru_phase(tid, bid * 48, xembbf + (size_t)t * 32768, h2prev, Wp0,
                  bi0, bh0, h2prev, h1slot, sm);
        gbar(cnt, gen, bk++);
        // ---- P2: per-b hid GEMV + attention -> z ----
        {
            const int b = bid;
            float* hv = sm;             // 1024
            float* hd = sm + 1024;      // 512
            float* wm = sm + 1536;      // 512
            float* sc = sm + 2048;      // 128
            const unsigned* h1row = (const unsigned*)(h1slot + (size_t)b * 1024);
            for (int k = tid; k < 512; k += 256) {
                unsigned u = h1row[k];
                hv[2 * k]     = __uint_as_float(u << 16);
                hv[2 * k + 1] = __uint_as_float(u & 0xFFFF0000u);
                wm[k] = wmlp[k];
            }
            __syncthreads();
            // hid[c] = sum_k h1[b][k] * Wh2cT[k][c]  (coalesced uint loads, 2 c/thread)
            {
                const int c2 = tid * 2;
                float a0 = 0, a1 = 0;
                #pragma unroll 8
                for (int k = 0; k < 1024; ++k) {
                    float h = hv[k];
                    unsigned u = *(const unsigned*)(Wh2cT + (size_t)k * 512 + c2);
                    a0 += h * __uint_as_float(u << 16);
                    a1 += h * __uint_as_float(u & 0xFFFF0000u);
                }
                hd[c2] = a0; hd[c2 + 1] = a1;
            }
            __syncthreads();
            // scores over S
            for (int s = w * 32; s < w * 32 + 32; ++s) {
                const short8 v8 = *(const short8*)(ctxpbf + ((size_t)s * 64 + b) * 512 + lane * 8);
                float acc = 0;
                #pragma unroll
                for (int e = 0; e < 8; ++e) {
                    int c = lane * 8 + e;
                    acc += tanh_(bf2f((ushort_t)v8[e]) + hd[c]) * wm[c];
                }
                acc = wred(acc);
                if (lane == 0) sc[s] = acc;
            }
            __syncthreads();
            if (w == 0) {
                float s0 = sc[lane], s1 = sc[lane + 64];
                float m = fmaxf(s0, s1);
                m = wmax(m); m = __shfl(m, 0);
                float e0 = __expf(s0 - m), e1 = __expf(s1 - m);
                float ssum = wred(e0 + e1); ssum = __shfl(ssum, 0);
                float inv = 1.0f / ssum;
                sc[lane] = e0 * inv; sc[lane + 64] = e1 * inv;
            }
            __syncthreads();
            {
                const int c2 = tid * 2;
                float a0 = 0, a1 = 0;
                #pragma unroll 8
                for (int s = 0; s < 128; ++s) {
                    float al = sc[s];
                    float2 cv = *(const float2*)(ctxf + ((size_t)s * 64 + b) * 512 + c2);
                    a0 += al * cv.x; a1 += al * cv.y;
                }
                unsigned pack = (unsigned)f2bf(a0) | (((unsigned)f2bf(a1)) << 16);
                __hip_atomic_store((unsigned*)zslot + b * 256 + tid, pack,
                                   __ATOMIC_RELAXED, __HIP_MEMORY_SCOPE_AGENT);
            }
        }
        gbar(cnt, gen, bk++);
        // ---- P3: GRU1 -> h2 (slot t+1) ----
        gru_phase(tid, bid * 48, zslot, h1slot, Wp1,
                  bi1, bh1, h1slot, h2ring + (size_t)(t + 1) * 65536, sm);
        gbar(cnt, gen, bk++);
    }
}

// ---------------------------------------------------------------------------
// fp32-in bf16-out tiled GEMM-NT for ctx_p precompute.
// ---------------------------------------------------------------------------
__global__ __launch_bounds__(256) void gemm_nt_bf(const float* __restrict__ A,
                                                  const float* __restrict__ Bw,
                                                  ushort_t* __restrict__ Cbf,
                                                  int N, int K) {
    __shared__ __align__(16) float As[16][68];
    __shared__ __align__(16) float Bs[16][68];
    const int tid = threadIdx.x;
    const int m0 = blockIdx.y * 64, n0 = blockIdx.x * 64;
    const int tx = tid & 15, ty = tid >> 4;
    const int lr = tid >> 2, lk = (tid & 3) << 2;
    float acc[4][4] = {};
    const float* Ap = A + (size_t)(m0 + lr) * K + lk;
    const float* Bp = Bw + (size_t)(n0 + lr) * K + lk;
    for (int kt = 0; kt < K; kt += 16) {
        float4 av = *(const float4*)(Ap + kt);
        float4 bv = *(const float4*)(Bp + kt);
        __syncthreads();
        As[lk + 0][lr] = av.x; As[lk + 1][lr] = av.y; As[lk + 2][lr] = av.z; As[lk + 3][lr] = av.w;
        Bs[lk + 0][lr] = bv.x; Bs[lk + 1][lr] = bv.y; Bs[lk + 2][lr] = bv.z; Bs[lk + 3][lr] = bv.w;
        __syncthreads();
        #pragma unroll
        for (int kk = 0; kk < 16; ++kk) {
            float4 a = *(const float4*)&As[kk][ty << 2];
            float4 b = *(const float4*)&Bs[kk][tx << 2];
            float ar[4] = {a.x, a.y, a.z, a.w};
            float br[4] = {b.x, b.y, b.z, b.w};
            #pragma unroll
            for (int i = 0; i < 4; ++i)
                #pragma unroll
                for (int j = 0; j < 4; ++j) acc[i][j] = fmaf(ar[i], br[j], acc[i][j]);
        }
    }
    #pragma unroll
    for (int i = 0; i < 4; ++i)
        #pragma unroll
        for (int j = 0; j < 4; ++j)
            Cbf[(size_t)(m0 + (ty << 2) + i) * N + n0 + (tx << 2) + j] = f2bf(acc[i][j]);
}

// ---------------------------------------------------------------------------
// bf16 MFMA GEMM-NT 128x128 tail. EPI==1: tanh(acc+bias)->bf16. EPI==2: LSE partials.
// ---------------------------------------------------------------------------
template <int EPI>
__global__ __launch_bounds__(256) void mfma_nt(const ushort_t* __restrict__ A,
                                               const ushort_t* __restrict__ Bw,
                                               const float* __restrict__ bias,
                                               ushort_t* __restrict__ Cbf,
                                               float2* __restrict__ pp,
                                               int N, int K, int NT) {
    __shared__ ushort_t As[128 * 72];
    __shared__ ushort_t Bs[128 * 72];
    __shared__ float smM[2][128], smS[2][128];
    const int tid = threadIdx.x;
    const int m0 = blockIdx.y * 128, n0 = blockIdx.x * 128;
    const int w = tid >> 6, lane = tid & 63;
    const int quad = lane >> 4, l16 = lane & 15;
    f32x4 acc[4][4] = {};
    for (int kc = 0; kc < K; kc += 64) {
        __syncthreads();
        #pragma unroll
        for (int i = 0; i < 4; ++i) {
            int cid = i * 256 + tid;
            int row = cid >> 3, c8 = cid & 7;
            uint4 va = *(const uint4*)(A + (size_t)(m0 + row) * K + kc + c8 * 8);
            *(uint4*)(&As[row * 72 + c8 * 8]) = va;
            uint4 vb = *(const uint4*)(Bw + (size_t)(n0 + row) * K + kc + c8 * 8);
            *(uint4*)(&Bs[row * 72 + c8 * 8]) = vb;
        }
        __syncthreads();
        #pragma unroll
        for (int ks = 0; ks < 2; ++ks) {
            short8 af[4], bfr[4];
            #pragma unroll
            for (int i = 0; i < 4; ++i)
                af[i] = *(const short8*)(&As[((w >> 1) * 64 + i * 16 + l16) * 72 + ks * 32 + quad * 8]);
            #pragma unroll
            for (int j = 0; j < 4; ++j)
                bfr[j] = *(const short8*)(&Bs[((w & 1) * 64 + j * 16 + l16) * 72 + ks * 32 + quad * 8]);
            #pragma unroll
            for (int i = 0; i < 4; ++i)
                #pragma unroll
                for (int j = 0; j < 4; ++j)
                    acc[i][j] = __builtin_amdgcn_mfma_f32_16x16x32_bf16(af[i], bfr[j], acc[i][j], 0, 0, 0);
        }
    }
    const int colbase = n0 + (w & 1) * 64;
    const int rowbase = m0 + (w >> 1) * 64;
    if (EPI == 1) {
        #pragma unroll
        for (int j = 0; j < 4; ++j) {
            int col = colbase + j * 16 + l16;
            float bv = bias[col];
            #pragma unroll
            for (int i = 0; i < 4; ++i)
                #pragma unroll
                for (int r = 0; r < 4; ++r) {
                    int row = rowbase + i * 16 + quad * 4 + r;
                    Cbf[(size_t)row * N + col] = f2bf(tanh_(acc[i][j][r] + bv));
                }
        }
    } else {
        float bv[4];
        #pragma unroll
        for (int j = 0; j < 4; ++j) bv[j] = bias[colbase + j * 16 + l16];
        #pragma unroll
        for (int i = 0; i < 4; ++i) {
            #pragma unroll
            for (int r = 0; r < 4; ++r) {
                float x0 = acc[i][0][r] + bv[0], x1 = acc[i][1][r] + bv[1];
                float x2 = acc[i][2][r] + bv[2], x3 = acc[i][3][r] + bv[3];
                float mx = fmaxf(fmaxf(x0, x1), fmaxf(x2, x3));
                #pragma unroll
                for (int o = 1; o < 16; o <<= 1) mx = fmaxf(mx, __shfl_xor(mx, o));
                float s = __expf(x0 - mx) + __expf(x1 - mx) + __expf(x2 - mx) + __expf(x3 - mx);
                #pragma unroll
                for (int o = 1; o < 16; o <<= 1) s += __shfl_xor(s, o);
                if (l16 == 0) {
                    int rr = (w >> 1) * 64 + i * 16 + quad * 4 + r;
                    smM[w & 1][rr] = mx;
                    smS[w & 1][rr] = s;
                }
            }
        }
        __syncthreads();
        if (tid < 128) {
            float ma = smM[0][tid], mb = smM[1][tid];
            float M = fmaxf(ma, mb);
            float S = smS[0][tid] * __expf(ma - M) + smS[1][tid] * __expf(mb - M);
            pp[(size_t)(m0 + tid) * NT + blockIdx.x] = make_float2(M, S);
        }
    }
}

__global__ __launch_bounds__(256) void conv_bf16(const float* __restrict__ src,
                                                 ushort_t* __restrict__ dst,
                                                 long long n) {
    long long base = ((long long)blockIdx.x * 256 + threadIdx.x) * 4;
    if (base >= n) return;
    float4 v = *(const float4*)(src + base);
    *(ushort2*)(dst + base) = make_ushort2(f2bf(v.x), f2bf(v.y));
    *(ushort2*)(dst + base + 2) = make_ushort2(f2bf(v.z), f2bf(v.w));
}

// pack GRU weights: row c = 3*jj+g -> [Wih[g*1024+jj][0:512] | Whh[g*1024+jj][0:1024]], bf16.
__global__ __launch_bounds__(256) void pack_gru(const float* __restrict__ Wih,
                                                const float* __restrict__ Whh,
                                                ushort_t* __restrict__ Wp) {
    const int c = blockIdx.x;           // 0..3071
    const int jj = c / 3, g = c % 3;
    const int src = g * 1024 + jj;
    ushort_t* dst = Wp + (size_t)c * 1536;
    for (int k = threadIdx.x; k < 512; k += 256) dst[k] = f2bf(Wih[(size_t)src * 512 + k]);
    for (int k = threadIdx.x; k < 1024; k += 256) dst[512 + k] = f2bf(Whh[(size_t)src * 1024 + k]);
}

// transpose+convert W_h2c [512 c][1024 k] fp32 -> [1024 k][512 c] bf16
__global__ __launch_bounds__(512) void pack_h2cT(const float* __restrict__ W,
                                                 ushort_t* __restrict__ WT) {
    const int k = blockIdx.x, c = threadIdx.x;
    WT[(size_t)k * 512 + c] = f2bf(W[(size_t)c * 1024 + k]);
}

__global__ __launch_bounds__(128) void gather_emb_bf(const float* __restrict__ emb,
                                                     const int* __restrict__ y,
                                                     ushort_t* __restrict__ xall) {
    const int r = blockIdx.x;
    const int tok = y[r];
    const float* src = emb + (size_t)tok * 512;
    ushort_t* dst = xall + (size_t)r * 512;
    int k = threadIdx.x * 4;
    float4 v = *(const float4*)(src + k);
    *(ushort2*)(dst + k) = make_ushort2(f2bf(v.x), f2bf(v.y));
    *(ushort2*)(dst + k + 2) = make_ushort2(f2bf(v.z), f2bf(v.w));
}

__global__ __launch_bounds__(64) void row_loss_k(const float2* __restrict__ pp,
                                                 const ushort_t* __restrict__ lg,
                                                 const ushort_t* __restrict__ Wvbf,
                                                 const float* __restrict__ bv,
                                                 const int* __restrict__ y,
                                                 float* __restrict__ rl) {
    const int r = blockIdx.x;
    const int lane = threadIdx.x;
    const int t = r / B_, b = r % B_;
    const int tgt = y[(t + 1) * B_ + b];
    float m = -1e30f;
    for (int i = lane; i < NT2; i += 64) m = fmaxf(m, pp[(size_t)r * NT2 + i].x);
    m = wmax(m); m = __shfl(m, 0);
    float s = 0;
    for (int i = lane; i < NT2; i += 64) {
        float2 p = pp[(size_t)r * NT2 + i];
        s += p.y * __expf(p.x - m);
    }
    s = wred(s);
    float d = 0;
    for (int k = lane; k < E_; k += 64)
        d += bf2f(lg[(size_t)r * E_ + k]) * bf2f(Wvbf[(size_t)tgt * E_ + k]);
    d = wred(d);
    if (lane == 0) {
        float lse = m + logf(s);
        rl[r] = (tgt != 0) ? (lse - (d + bv[tgt])) : 0.0f;
    }
}

__global__ __launch_bounds__(256) void sum_k(const float* __restrict__ rl, float* __restrict__ out) {
    float s = 0;
    for (int i = threadIdx.x; i < R_; i += 256) s += rl[i];
    __shared__ float red[4];
    s = wred(s);
    if ((threadIdx.x & 63) == 0) red[threadIdx.x >> 6] = s;
    __syncthreads();
    if (threadIdx.x == 0) out[0] = red[0] + red[1] + red[2] + red[3];
}

extern "C" void kernel_launch(void* const* d_in, const int* in_sizes, int n_in,
                              void* d_out, int out_size, void* d_ws, size_t ws_size,
                              hipStream_t stream) {
    const int*   y     = (const int*)d_in[0];
    const float* ctx   = (const float*)d_in[1];
    const float* emb   = (const float*)d_in[2];
    const float* W_ih0 = (const float*)d_in[3];
    const float* W_hh0 = (const float*)d_in[4];
    const float* b_ih0 = (const float*)d_in[5];
    const float* b_hh0 = (const float*)d_in[6];
    const float* W_ih1 = (const float*)d_in[7];
    const float* W_hh1 = (const float*)d_in[8];
    const float* b_ih1 = (const float*)d_in[9];
    const float* b_hh1 = (const float*)d_in[10];
    const float* W_c2c = (const float*)d_in[11];
    const float* W_h2c = (const float*)d_in[12];
    const float* w_mlp = (const float*)d_in[13];
    const float* W_h2o = (const float*)d_in[14];
    const float* b_h2o = (const float*)d_in[15];
    const float* W_o2p = (const float*)d_in[16];
    const float* b_o2p = (const float*)d_in[17];
    float* out = (float*)d_out;

    // ---- workspace layout: loop-phase view and tail-phase view share region A ----
    char* base = (char*)d_ws;
    int* bar = (int*)base;                         // 256 B
    char* regA = base + 256;
    // loop view of region A:
    ushort_t* ctxpbf = (ushort_t*)(regA);                        //  8,388,608
    ushort_t* xembbf = (ushort_t*)(regA + 8388608);              //  6,488,064
    ushort_t* Wp0    = (ushort_t*)(regA + 14876672);             //  9,437,184
    ushort_t* Wp1    = (ushort_t*)(regA + 24313856);             //  9,437,184
    ushort_t* Wh2cT  = (ushort_t*)(regA + 33751040);             //  1,048,576
    ushort_t* h1ring = (ushort_t*)(regA + 34799616);             // 12,976,128
    ushort_t* zring  = (ushort_t*)(regA + 47775744);             //  6,488,064  -> end 54,263,808
    // tail view of region A (live only after decode_persist):
    ushort_t* Wo2pbf = (ushort_t*)(regA);                        // 32,768,000
    ushort_t* Wh2obf = (ushort_t*)(regA + 32768000);             //  1,048,576
    ushort_t* lg_bf  = (ushort_t*)(regA + 33816576);             //  6,553,600
    float2*   pp     = (float2*)(regA + 40370176);               // 12,800,000
    float*    rl     = (float*)(regA + 53170176);                //     25,344
    // region B (live across both phases):
    ushort_t* h2ring = (ushort_t*)(regA + 54263808);             // 13,238,272 (6464 rows x 1024)

    // ---- init ----
    hipMemsetAsync(bar, 0, 256, stream);
    hipMemsetAsync(h2ring, 0, (size_t)B_ * H_ * 2, stream);                       // slot 0 = h_init
    hipMemsetAsync(h2ring + (size_t)(B_ + R_) * H_, 0, (size_t)(MP_ - R_) * H_ * 2, stream); // pad rows

    // ---- precompute (loop-phase buffers) ----
    gemm_nt_bf<<<dim3(C_ / 64, (S_ * B_) / 64), 256, 0, stream>>>(ctx, W_c2c, ctxpbf, C_, C_);
    gather_emb_bf<<<R_, 128, 0, stream>>>(emb, y, xembbf);
    pack_gru<<<3072, 256, 0, stream>>>(W_ih0, W_hh0, Wp0);
    pack_gru<<<3072, 256, 0, stream>>>(W_ih1, W_hh1, Wp1);
    pack_h2cT<<<1024, 512, 0, stream>>>(W_h2c, Wh2cT);

    // ---- persistent sequential decode loop ----
    decode_persist<<<NBLK, 256, 0, stream>>>(xembbf, ctxpbf, ctx, Wp0, Wp1, Wh2cT,
                                             b_ih0, b_hh0, b_ih1, b_hh1, w_mlp,
                                             h1ring, zring, h2ring, bar, bar + 1);

    // ---- tail-phase conversions (overlay loop buffers, safe after decode) ----
    conv_bf16<<<((size_t)E_ * H_ / 4 + 255) / 256, 256, 0, stream>>>(W_h2o, Wh2obf, (long long)E_ * H_);
    conv_bf16<<<((size_t)V_ * E_ / 4 + 255) / 256, 256, 0, stream>>>(W_o2p, Wo2pbf, (long long)V_ * E_);

    // ---- batched tail (bf16 MFMA) ----
    mfma_nt<1><<<dim3(E_ / 128, MP_ / 128), 256, 0, stream>>>(h2ring + (size_t)B_ * H_, Wh2obf, b_h2o,
                                                              lg_bf, nullptr, E_, H_, 0);
    mfma_nt<2><<<dim3(V_ / 128, MP_ / 128), 256, 0, stream>>>(lg_bf, Wo2pbf, b_o2p,
                                                              nullptr, pp, V_, E_, NT2);
    row_loss_k<<<R_, 64, 0, stream>>>(pp, lg_bf, Wo2pbf, b_o2p, y, rl);
    sum_k<<<1, 256, 0, stream>>>(rl, out);
}

// Round 5
// 11434.961 us; speedup vs baseline: 2.9632x; 2.9632x over previous
//
#include <hip/hip_runtime.h>
#include <math.h>

#define T_ 100
#define B_ 64
#define S_ 128
#define E_ 512
#define H_ 1024
#define C_ 512
#define V_ 32000
#define TS_ 99            // T-1 steps
#define R_ (TS_ * B_)     // 6336 rows
#define MP_ 6400          // rows padded to multiple of 128 for MFMA
#define NT2 250           // vocab n-tiles of 128
#define NBLK 64           // persistent-kernel grid size

typedef unsigned short ushort_t;
typedef __attribute__((ext_vector_type(8))) short short8;
typedef __attribute__((ext_vector_type(4))) float f32x4;

__device__ __forceinline__ float sigm_(float x) { return 1.0f / (1.0f + __expf(-x)); }
__device__ __forceinline__ float tanh_(float x) { float e = __expf(2.0f * x); return 1.0f - 2.0f / (e + 1.0f); }
__device__ __forceinline__ ushort_t f2bf(float f) {
    unsigned u = __float_as_uint(f);
    unsigned r = (u + 0x7FFF + ((u >> 16) & 1)) >> 16;
    return (ushort_t)r;
}
__device__ __forceinline__ float bf2f(ushort_t u) { return __uint_as_float(((unsigned)u) << 16); }

__device__ __forceinline__ float wred(float v) {
    #pragma unroll
    for (int o = 32; o; o >>= 1) v += __shfl_down(v, o);
    return v;
}
__device__ __forceinline__ float wmax(float v) {
    #pragma unroll
    for (int o = 32; o; o >>= 1) v = fmaxf(v, __shfl_down(v, o));
    return v;
}

// Grid barrier with NO cache-maintenance ops. Data plane: sc1 (agent-scope
// relaxed atomic) stores to VIRGIN ring addresses -> consumers' plain loads
// can never hit a stale line. Control plane: both the arrival counter and the
// generation word are accessed ONLY with atomic RMWs, which execute at the
// device coherence point -> ~0.3us visibility, no L2 invalidates (a relaxed
// atomic LOAD would be cached in the spinner's XCD L2 and only observe the
// update on eviction -- that was round 4's ~112us/barrier failure).
__device__ __forceinline__ void gbar(int* cnt, int* gen, int k) {
    __syncthreads();   // drains vmcnt -> this block's sc1 stores are at the coherent point
    if (threadIdx.x == 0) {
        asm volatile("" ::: "memory");
        __builtin_amdgcn_s_waitcnt(0);
        int v = __hip_atomic_fetch_add(cnt, 1, __ATOMIC_RELAXED, __HIP_MEMORY_SCOPE_AGENT);
        if (v == k * NBLK + (NBLK - 1)) {
            __hip_atomic_fetch_add(gen, 1, __ATOMIC_RELAXED, __HIP_MEMORY_SCOPE_AGENT);
        } else {
            while (__hip_atomic_fetch_add(gen, 0, __ATOMIC_RELAXED, __HIP_MEMORY_SCOPE_AGENT) < k + 1)
                __builtin_amdgcn_s_sleep(2);
        }
        asm volatile("" ::: "memory");
    }
    __syncthreads();
}

// ---------------------------------------------------------------------------
// Fused GRU phase. 64 blocks, block owns 16 j (48 packed rows).
// Wp packed [3072][1536] bf16: row c=3*jj+g = [Wih[g*1024+jj][0:512] | Whh[g*1024+jj][0:1024]].
// Outputs h (bf16) via sc1 stores into a virgin ring slot.
// ---------------------------------------------------------------------------
__device__ __forceinline__ void gru_phase(
    int tid, int c0,
    const ushort_t* __restrict__ ax,   // [64][512] bf16
    const ushort_t* __restrict__ ah,   // [64][1024] bf16
    const ushort_t* __restrict__ Wp,
    const float* __restrict__ bi, const float* __restrict__ bh,
    const ushort_t* __restrict__ hpbf, // [64][1024] bf16 prev h
    ushort_t* __restrict__ hout,       // [64][1024] bf16 ring slot (sc1 stores)
    float* __restrict__ sm)            // 12288 floats LDS
{
    const int w = tid >> 6, lane = tid & 63, quad = lane >> 4, l16 = lane & 15;
    f32x4 accX[12] = {};
    f32x4 accH[12] = {};
    const int kc0 = w * 12;   // 48 kc slices: kc<16 -> x (K=512), kc>=16 -> h (K=1024)
    #pragma unroll
    for (int i = 0; i < 12; ++i) {
        const int kc = kc0 + i;
        const int kw = kc * 32 + quad * 8;
        short8 bfr[3];
        #pragma unroll
        for (int ct = 0; ct < 3; ++ct)
            bfr[ct] = *(const short8*)(Wp + (size_t)(c0 + ct * 16 + l16) * 1536 + kw);
        short8 af[4];
        if (kc < 16) {
            #pragma unroll
            for (int mt = 0; mt < 4; ++mt)
                af[mt] = *(const short8*)(ax + (size_t)(mt * 16 + l16) * 512 + kw);
            #pragma unroll
            for (int mt = 0; mt < 4; ++mt)
                #pragma unroll
                for (int ct = 0; ct < 3; ++ct)
                    accX[mt * 3 + ct] = __builtin_amdgcn_mfma_f32_16x16x32_bf16(af[mt], bfr[ct], accX[mt * 3 + ct], 0, 0, 0);
        } else {
            const int ko = (kc - 16) * 32 + quad * 8;
            #pragma unroll
            for (int mt = 0; mt < 4; ++mt)
                af[mt] = *(const short8*)(ah + (size_t)(mt * 16 + l16) * 1024 + ko);
            #pragma unroll
            for (int mt = 0; mt < 4; ++mt)
                #pragma unroll
                for (int ct = 0; ct < 3; ++ct)
                    accH[mt * 3 + ct] = __builtin_amdgcn_mfma_f32_16x16x32_bf16(af[mt], bfr[ct], accH[mt * 3 + ct], 0, 0, 0);
        }
    }
    // LDS reduce round 1: X partials
    #pragma unroll
    for (int p = 0; p < 12; ++p)
        #pragma unroll
        for (int r = 0; r < 4; ++r)
            sm[w * 3072 + p * 256 + (quad * 4 + r) * 16 + l16] = accX[p][r];
    __syncthreads();
    float Xg[2][2][3], Hg[2][2][3];
    #pragma unroll
    for (int q = 0; q < 2; ++q) {
        int o = q * 256 + tid, b = o >> 3, jp = o & 7;
        int mt3 = (b >> 4) * 3, e0 = (b & 15) * 16;
        #pragma unroll
        for (int jj = 0; jj < 2; ++jj)
            #pragma unroll
            for (int g = 0; g < 3; ++g) {
                int c = (jp * 2 + jj) * 3 + g;
                int p = mt3 + (c >> 4), e = e0 + (c & 15);
                Xg[q][jj][g] = sm[p * 256 + e] + sm[3072 + p * 256 + e]
                             + sm[6144 + p * 256 + e] + sm[9216 + p * 256 + e];
            }
    }
    __syncthreads();
    // LDS reduce round 2: H partials
    #pragma unroll
    for (int p = 0; p < 12; ++p)
        #pragma unroll
        for (int r = 0; r < 4; ++r)
            sm[w * 3072 + p * 256 + (quad * 4 + r) * 16 + l16] = accH[p][r];
    __syncthreads();
    #pragma unroll
    for (int q = 0; q < 2; ++q) {
        int o = q * 256 + tid, b = o >> 3, jp = o & 7;
        int mt3 = (b >> 4) * 3, e0 = (b & 15) * 16;
        #pragma unroll
        for (int jj = 0; jj < 2; ++jj)
            #pragma unroll
            for (int g = 0; g < 3; ++g) {
                int c = (jp * 2 + jj) * 3 + g;
                int p = mt3 + (c >> 4), e = e0 + (c & 15);
                Hg[q][jj][g] = sm[p * 256 + e] + sm[3072 + p * 256 + e]
                             + sm[6144 + p * 256 + e] + sm[9216 + p * 256 + e];
            }
    }
    const int j0 = c0 / 3;
    #pragma unroll
    for (int q = 0; q < 2; ++q) {
        int o = q * 256 + tid, b = o >> 3, jp = o & 7;
        unsigned pack = 0;
        #pragma unroll
        for (int jj = 0; jj < 2; ++jj) {
            int j = j0 + jp * 2 + jj;
            float r = sigm_(Xg[q][jj][0] + Hg[q][jj][0] + bi[j] + bh[j]);
            float z = sigm_(Xg[q][jj][1] + Hg[q][jj][1] + bi[1024 + j] + bh[1024 + j]);
            float n = tanh_(Xg[q][jj][2] + bi[2048 + j] + r * (Hg[q][jj][2] + bh[2048 + j]));
            float hp = bf2f(hpbf[(size_t)b * 1024 + j]);
            float h = (1.0f - z) * n + z * hp;
            pack |= ((unsigned)f2bf(h)) << (16 * jj);
        }
        __hip_atomic_store((unsigned*)(hout + (size_t)b * 1024) + (j0 >> 1) + jp, pack,
                           __ATOMIC_RELAXED, __HIP_MEMORY_SCOPE_AGENT);
    }
}

// ---------------------------------------------------------------------------
// Persistent decode loop: 64 blocks x 256 threads, 4 phases + 4 barriers/step.
// ---------------------------------------------------------------------------
__global__ __launch_bounds__(256, 1) void decode_persist(
    const ushort_t* __restrict__ xembbf,   // [R_][512]
    const ushort_t* __restrict__ ctxpbf,   // [S*B][512]
    const ushort_t* __restrict__ ctxbf,    // [S*B][512]
    const ushort_t* __restrict__ Wp0,
    const ushort_t* __restrict__ Wp1,
    const ushort_t* __restrict__ Wh2cbf,   // [512 c][1024 k] bf16 row-major
    const float* __restrict__ bi0, const float* __restrict__ bh0,
    const float* __restrict__ bi1, const float* __restrict__ bh1,
    const float* __restrict__ wmlp,
    ushort_t* __restrict__ h1ring,         // [99][64][1024]
    ushort_t* __restrict__ zring,          // [99][64][512]
    ushort_t* __restrict__ hidring,        // [99][64][512]
    ushort_t* __restrict__ h2ring,         // [100 slots][64][1024]; slot0 = zeros
    int* cnt, int* gen)
{
    __shared__ float sm[12288];   // 48 KB, reused by all phases
    const int bid = blockIdx.x, tid = threadIdx.x;
    const int w = tid >> 6, lane = tid & 63;
    const int quad = lane >> 4, l16 = lane & 15;
    int bk = 0;
    for (int t = 0; t < TS_; ++t) {
        const ushort_t* h2prev = h2ring + (size_t)t * 65536;
        ushort_t* h1slot  = h1ring + (size_t)t * 65536;
        ushort_t* zslot   = zring + (size_t)t * 32768;
        ushort_t* hidslot = hidring + (size_t)t * 32768;
        // ---- P1: GRU0 -> h1 ----
        gru_phase(tid, bid * 48, xembbf + (size_t)t * 32768, h2prev, Wp0,
                  bi0, bh0, h2prev, h1slot, sm);
        gbar(cnt, gen, bk++);
        // ---- P2: hid = h1 @ W_h2c^T (32 blocks, MFMA) ----
        if (bid < 32) {
            const int c0 = bid * 16;
            f32x4 acc[4] = {};
            #pragma unroll
            for (int i = 0; i < 8; ++i) {
                const int ko = (w * 8 + i) * 32 + quad * 8;
                short8 bfr = *(const short8*)(Wh2cbf + (size_t)(c0 + l16) * 1024 + ko);
                #pragma unroll
                for (int mt = 0; mt < 4; ++mt) {
                    short8 af = *(const short8*)(h1slot + (size_t)(mt * 16 + l16) * 1024 + ko);
                    acc[mt] = __builtin_amdgcn_mfma_f32_16x16x32_bf16(af, bfr, acc[mt], 0, 0, 0);
                }
            }
            #pragma unroll
            for (int mt = 0; mt < 4; ++mt)
                #pragma unroll
                for (int r = 0; r < 4; ++r)
                    sm[w * 1024 + mt * 256 + (quad * 4 + r) * 16 + l16] = acc[mt][r];
            __syncthreads();
            #pragma unroll
            for (int mt = 0; mt < 4; ++mt) {
                float v = sm[mt * 256 + tid] + sm[1024 + mt * 256 + tid]
                        + sm[2048 + mt * 256 + tid] + sm[3072 + mt * 256 + tid];
                int b = mt * 16 + (tid >> 4), c = c0 + (tid & 15);
                __hip_atomic_store(hidslot + (size_t)b * 512 + c, f2bf(v),
                                   __ATOMIC_RELAXED, __HIP_MEMORY_SCOPE_AGENT);
            }
        }
        gbar(cnt, gen, bk++);
        // ---- P3: attention -> z (64 blocks, one per b) ----
        {
            const int b = bid;
            float* hd = sm;             // 512
            float* wm = sm + 512;       // 512
            float* sc = sm + 1024;      // 128
            const ushort_t* hidrow = hidslot + (size_t)b * 512;
            for (int k2 = tid; k2 < 512; k2 += 256) { hd[k2] = bf2f(hidrow[k2]); wm[k2] = wmlp[k2]; }
            __syncthreads();
            for (int s = w * 32; s < w * 32 + 32; ++s) {
                const short8 v8 = *(const short8*)(ctxpbf + ((size_t)s * 64 + b) * 512 + lane * 8);
                float acc = 0;
                #pragma unroll
                for (int e = 0; e < 8; ++e) {
                    int c = lane * 8 + e;
                    acc += tanh_(bf2f((ushort_t)v8[e]) + hd[c]) * wm[c];
                }
                acc = wred(acc);
                if (lane == 0) sc[s] = acc;
            }
            __syncthreads();
            if (w == 0) {
                float s0 = sc[lane], s1 = sc[lane + 64];
                float m = fmaxf(s0, s1);
                m = wmax(m); m = __shfl(m, 0);
                float e0 = __expf(s0 - m), e1 = __expf(s1 - m);
                float ssum = wred(e0 + e1); ssum = __shfl(ssum, 0);
                float inv = 1.0f / ssum;
                sc[lane] = e0 * inv; sc[lane + 64] = e1 * inv;
            }
            __syncthreads();
            {
                const int c2 = tid * 2;
                float a0 = 0, a1 = 0;
                #pragma unroll 8
                for (int s = 0; s < 128; ++s) {
                    float al = sc[s];
                    ushort2 u = *(const ushort2*)(ctxbf + ((size_t)s * 64 + b) * 512 + c2);
                    a0 += al * bf2f(u.x); a1 += al * bf2f(u.y);
                }
                unsigned pack = (unsigned)f2bf(a0) | (((unsigned)f2bf(a1)) << 16);
                __hip_atomic_store((unsigned*)zslot + b * 256 + tid, pack,
                                   __ATOMIC_RELAXED, __HIP_MEMORY_SCOPE_AGENT);
            }
        }
        gbar(cnt, gen, bk++);
        // ---- P4: GRU1 -> h2 (slot t+1) ----
        gru_phase(tid, bid * 48, zslot, h1slot, Wp1,
                  bi1, bh1, h1slot, h2ring + (size_t)(t + 1) * 65536, sm);
        gbar(cnt, gen, bk++);
    }
}

// ---------------------------------------------------------------------------
// fp32-in bf16-out tiled GEMM-NT for ctx_p precompute.
// ---------------------------------------------------------------------------
__global__ __launch_bounds__(256) void gemm_nt_bf(const float* __restrict__ A,
                                                  const float* __restrict__ Bw,
                                                  ushort_t* __restrict__ Cbf,
                                                  int N, int K) {
    __shared__ __align__(16) float As[16][68];
    __shared__ __align__(16) float Bs[16][68];
    const int tid = threadIdx.x;
    const int m0 = blockIdx.y * 64, n0 = blockIdx.x * 64;
    const int tx = tid & 15, ty = tid >> 4;
    const int lr = tid >> 2, lk = (tid & 3) << 2;
    float acc[4][4] = {};
    const float* Ap = A + (size_t)(m0 + lr) * K + lk;
    const float* Bp = Bw + (size_t)(n0 + lr) * K + lk;
    for (int kt = 0; kt < K; kt += 16) {
        float4 av = *(const float4*)(Ap + kt);
        float4 bv = *(const float4*)(Bp + kt);
        __syncthreads();
        As[lk + 0][lr] = av.x; As[lk + 1][lr] = av.y; As[lk + 2][lr] = av.z; As[lk + 3][lr] = av.w;
        Bs[lk + 0][lr] = bv.x; Bs[lk + 1][lr] = bv.y; Bs[lk + 2][lr] = bv.z; Bs[lk + 3][lr] = bv.w;
        __syncthreads();
        #pragma unroll
        for (int kk = 0; kk < 16; ++kk) {
            float4 a = *(const float4*)&As[kk][ty << 2];
            float4 b = *(const float4*)&Bs[kk][tx << 2];
            float ar[4] = {a.x, a.y, a.z, a.w};
            float br[4] = {b.x, b.y, b.z, b.w};
            #pragma unroll
            for (int i = 0; i < 4; ++i)
                #pragma unroll
                for (int j = 0; j < 4; ++j) acc[i][j] = fmaf(ar[i], br[j], acc[i][j]);
        }
    }
    #pragma unroll
    for (int i = 0; i < 4; ++i)
        #pragma unroll
        for (int j = 0; j < 4; ++j)
            Cbf[(size_t)(m0 + (ty << 2) + i) * N + n0 + (tx << 2) + j] = f2bf(acc[i][j]);
}

// ---------------------------------------------------------------------------
// bf16 MFMA GEMM-NT 128x128 tail. EPI==1: tanh(acc+bias)->bf16. EPI==2: LSE partials.
// ---------------------------------------------------------------------------
template <int EPI>
__global__ __launch_bounds__(256) void mfma_nt(const ushort_t* __restrict__ A,
                                               const ushort_t* __restrict__ Bw,
                                               const float* __restrict__ bias,
                                               ushort_t* __restrict__ Cbf,
                                               float2* __restrict__ pp,
                                               int N, int K, int NT) {
    __shared__ ushort_t As[128 * 72];
    __shared__ ushort_t Bs[128 * 72];
    __shared__ float smM[2][128], smS[2][128];
    const int tid = threadIdx.x;
    const int m0 = blockIdx.y * 128, n0 = blockIdx.x * 128;
    const int w = tid >> 6, lane = tid & 63;
    const int quad = lane >> 4, l16 = lane & 15;
    f32x4 acc[4][4] = {};
    for (int kc = 0; kc < K; kc += 64) {
        __syncthreads();
        #pragma unroll
        for (int i = 0; i < 4; ++i) {
            int cid = i * 256 + tid;
            int row = cid >> 3, c8 = cid & 7;
            uint4 va = *(const uint4*)(A + (size_t)(m0 + row) * K + kc + c8 * 8);
            *(uint4*)(&As[row * 72 + c8 * 8]) = va;
            uint4 vb = *(const uint4*)(Bw + (size_t)(n0 + row) * K + kc + c8 * 8);
            *(uint4*)(&Bs[row * 72 + c8 * 8]) = vb;
        }
        __syncthreads();
        #pragma unroll
        for (int ks = 0; ks < 2; ++ks) {
            short8 af[4], bfr[4];
            #pragma unroll
            for (int i = 0; i < 4; ++i)
                af[i] = *(const short8*)(&As[((w >> 1) * 64 + i * 16 + l16) * 72 + ks * 32 + quad * 8]);
            #pragma unroll
            for (int j = 0; j < 4; ++j)
                bfr[j] = *(const short8*)(&Bs[((w & 1) * 64 + j * 16 + l16) * 72 + ks * 32 + quad * 8]);
            #pragma unroll
            for (int i = 0; i < 4; ++i)
                #pragma unroll
                for (int j = 0; j < 4; ++j)
                    acc[i][j] = __builtin_amdgcn_mfma_f32_16x16x32_bf16(af[i], bfr[j], acc[i][j], 0, 0, 0);
        }
    }
    const int colbase = n0 + (w & 1) * 64;
    const int rowbase = m0 + (w >> 1) * 64;
    if (EPI == 1) {
        #pragma unroll
        for (int j = 0; j < 4; ++j) {
            int col = colbase + j * 16 + l16;
            float bv = bias[col];
            #pragma unroll
            for (int i = 0; i < 4; ++i)
                #pragma unroll
                for (int r = 0; r < 4; ++r) {
                    int row = rowbase + i * 16 + quad * 4 + r;
                    Cbf[(size_t)row * N + col] = f2bf(tanh_(acc[i][j][r] + bv));
                }
        }
    } else {
        float bv[4];
        #pragma unroll
        for (int j = 0; j < 4; ++j) bv[j] = bias[colbase + j * 16 + l16];
        #pragma unroll
        for (int i = 0; i < 4; ++i) {
            #pragma unroll
            for (int r = 0; r < 4; ++r) {
                float x0 = acc[i][0][r] + bv[0], x1 = acc[i][1][r] + bv[1];
                float x2 = acc[i][2][r] + bv[2], x3 = acc[i][3][r] + bv[3];
                float mx = fmaxf(fmaxf(x0, x1), fmaxf(x2, x3));
                #pragma unroll
                for (int o = 1; o < 16; o <<= 1) mx = fmaxf(mx, __shfl_xor(mx, o));
                float s = __expf(x0 - mx) + __expf(x1 - mx) + __expf(x2 - mx) + __expf(x3 - mx);
                #pragma unroll
                for (int o = 1; o < 16; o <<= 1) s += __shfl_xor(s, o);
                if (l16 == 0) {
                    int rr = (w >> 1) * 64 + i * 16 + quad * 4 + r;
                    smM[w & 1][rr] = mx;
                    smS[w & 1][rr] = s;
                }
            }
        }
        __syncthreads();
        if (tid < 128) {
            float ma = smM[0][tid], mb = smM[1][tid];
            float M = fmaxf(ma, mb);
            float S = smS[0][tid] * __expf(ma - M) + smS[1][tid] * __expf(mb - M);
            pp[(size_t)(m0 + tid) * NT + blockIdx.x] = make_float2(M, S);
        }
    }
}

__global__ __launch_bounds__(256) void conv_bf16(const float* __restrict__ src,
                                                 ushort_t* __restrict__ dst,
                                                 long long n) {
    long long base = ((long long)blockIdx.x * 256 + threadIdx.x) * 4;
    if (base >= n) return;
    float4 v = *(const float4*)(src + base);
    *(ushort2*)(dst + base) = make_ushort2(f2bf(v.x), f2bf(v.y));
    *(ushort2*)(dst + base + 2) = make_ushort2(f2bf(v.z), f2bf(v.w));
}

// pack GRU weights: row c = 3*jj+g -> [Wih[g*1024+jj][0:512] | Whh[g*1024+jj][0:1024]], bf16.
__global__ __launch_bounds__(256) void pack_gru(const float* __restrict__ Wih,
                                                const float* __restrict__ Whh,
                                                ushort_t* __restrict__ Wp) {
    const int c = blockIdx.x;           // 0..3071
    const int jj = c / 3, g = c % 3;
    const int src = g * 1024 + jj;
    ushort_t* dst = Wp + (size_t)c * 1536;
    for (int k = threadIdx.x; k < 512; k += 256) dst[k] = f2bf(Wih[(size_t)src * 512 + k]);
    for (int k = threadIdx.x; k < 1024; k += 256) dst[512 + k] = f2bf(Whh[(size_t)src * 1024 + k]);
}

__global__ __launch_bounds__(128) void gather_emb_bf(const float* __restrict__ emb,
                                                     const int* __restrict__ y,
                                                     ushort_t* __restrict__ xall) {
    const int r = blockIdx.x;
    const int tok = y[r];
    const float* src = emb + (size_t)tok * 512;
    ushort_t* dst = xall + (size_t)r * 512;
    int k = threadIdx.x * 4;
    float4 v = *(const float4*)(src + k);
    *(ushort2*)(dst + k) = make_ushort2(f2bf(v.x), f2bf(v.y));
    *(ushort2*)(dst + k + 2) = make_ushort2(f2bf(v.z), f2bf(v.w));
}

__global__ __launch_bounds__(64) void row_loss_k(const float2* __restrict__ pp,
                                                 const ushort_t* __restrict__ lg,
                                                 const ushort_t* __restrict__ Wvbf,
                                                 const float* __restrict__ bv,
                                                 const int* __restrict__ y,
                                                 float* __restrict__ rl) {
    const int r = blockIdx.x;
    const int lane = threadIdx.x;
    const int t = r / B_, b = r % B_;
    const int tgt = y[(t + 1) * B_ + b];
    float m = -1e30f;
    for (int i = lane; i < NT2; i += 64) m = fmaxf(m, pp[(size_t)r * NT2 + i].x);
    m = wmax(m); m = __shfl(m, 0);
    float s = 0;
    for (int i = lane; i < NT2; i += 64) {
        float2 p = pp[(size_t)r * NT2 + i];
        s += p.y * __expf(p.x - m);
    }
    s = wred(s);
    float d = 0;
    for (int k = lane; k < E_; k += 64)
        d += bf2f(lg[(size_t)r * E_ + k]) * bf2f(Wvbf[(size_t)tgt * E_ + k]);
    d = wred(d);
    if (lane == 0) {
        float lse = m + logf(s);
        rl[r] = (tgt != 0) ? (lse - (d + bv[tgt])) : 0.0f;
    }
}

__global__ __launch_bounds__(256) void sum_k(const float* __restrict__ rl, float* __restrict__ out) {
    float s = 0;
    for (int i = threadIdx.x; i < R_; i += 256) s += rl[i];
    __shared__ float red[4];
    s = wred(s);
    if ((threadIdx.x & 63) == 0) red[threadIdx.x >> 6] = s;
    __syncthreads();
    if (threadIdx.x == 0) out[0] = red[0] + red[1] + red[2] + red[3];
}

extern "C" void kernel_launch(void* const* d_in, const int* in_sizes, int n_in,
                              void* d_out, int out_size, void* d_ws, size_t ws_size,
                              hipStream_t stream) {
    const int*   y     = (const int*)d_in[0];
    const float* ctx   = (const float*)d_in[1];
    const float* emb   = (const float*)d_in[2];
    const float* W_ih0 = (const float*)d_in[3];
    const float* W_hh0 = (const float*)d_in[4];
    const float* b_ih0 = (const float*)d_in[5];
    const float* b_hh0 = (const float*)d_in[6];
    const float* W_ih1 = (const float*)d_in[7];
    const float* W_hh1 = (const float*)d_in[8];
    const float* b_ih1 = (const float*)d_in[9];
    const float* b_hh1 = (const float*)d_in[10];
    const float* W_c2c = (const float*)d_in[11];
    const float* W_h2c = (const float*)d_in[12];
    const float* w_mlp = (const float*)d_in[13];
    const float* W_h2o = (const float*)d_in[14];
    const float* b_h2o = (const float*)d_in[15];
    const float* W_o2p = (const float*)d_in[16];
    const float* b_o2p = (const float*)d_in[17];
    float* out = (float*)d_out;

    // ---- workspace layout: loop-phase view and tail-phase view share region A ----
    char* base = (char*)d_ws;
    int* bar = (int*)base;                         // 256 B
    char* regA = base + 256;
    // loop view of region A:
    ushort_t* ctxpbf  = (ushort_t*)(regA);                       //  8,388,608
    ushort_t* ctxbf   = (ushort_t*)(regA + 8388608);             //  8,388,608
    ushort_t* xembbf  = (ushort_t*)(regA + 16777216);            //  6,488,064
    ushort_t* Wp0     = (ushort_t*)(regA + 23265280);            //  9,437,184
    ushort_t* Wp1     = (ushort_t*)(regA + 32702464);            //  9,437,184
    ushort_t* Wh2cbf  = (ushort_t*)(regA + 42139648);            //  1,048,576
    ushort_t* h1ring  = (ushort_t*)(regA + 43188224);            // 12,976,128
    ushort_t* zring   = (ushort_t*)(regA + 56164352);            //  6,488,064
    ushort_t* hidring = (ushort_t*)(regA + 62652416);            //  6,488,064 -> end 69,140,480
    // tail view of region A (live only after decode_persist):
    ushort_t* Wo2pbf  = (ushort_t*)(regA);                       // 32,768,000
    ushort_t* Wh2obf  = (ushort_t*)(regA + 32768000);            //  1,048,576
    ushort_t* lg_bf   = (ushort_t*)(regA + 33816576);            //  6,553,600
    float2*   pp      = (float2*)(regA + 40370176);              // 12,800,000
    float*    rl      = (float*)(regA + 53170176);               //     25,344
    // region B (live across both phases):
    ushort_t* h2ring  = (ushort_t*)(regA + 69140480);            // 13,238,272 (6464 rows x 1024)

    // ---- init ----
    hipMemsetAsync(bar, 0, 256, stream);
    hipMemsetAsync(h2ring, 0, (size_t)B_ * H_ * 2, stream);                       // slot 0 = h_init
    hipMemsetAsync(h2ring + (size_t)(B_ + R_) * H_, 0, (size_t)(MP_ - R_) * H_ * 2, stream); // pad rows

    // ---- precompute (loop-phase buffers) ----
    gemm_nt_bf<<<dim3(C_ / 64, (S_ * B_) / 64), 256, 0, stream>>>(ctx, W_c2c, ctxpbf, C_, C_);
    conv_bf16<<<((size_t)S_ * B_ * C_ / 4 + 255) / 256, 256, 0, stream>>>(ctx, ctxbf, (long long)S_ * B_ * C_);
    gather_emb_bf<<<R_, 128, 0, stream>>>(emb, y, xembbf);
    pack_gru<<<3072, 256, 0, stream>>>(W_ih0, W_hh0, Wp0);
    pack_gru<<<3072, 256, 0, stream>>>(W_ih1, W_hh1, Wp1);
    conv_bf16<<<((size_t)C_ * H_ / 4 + 255) / 256, 256, 0, stream>>>(W_h2c, Wh2cbf, (long long)C_ * H_);

    // ---- persistent sequential decode loop ----
    decode_persist<<<NBLK, 256, 0, stream>>>(xembbf, ctxpbf, ctxbf, Wp0, Wp1, Wh2cbf,
                                             b_ih0, b_hh0, b_ih1, b_hh1, w_mlp,
                                             h1ring, zring, hidring, h2ring, bar, bar + 1);

    // ---- tail-phase conversions (overlay loop buffers, safe after decode) ----
    conv_bf16<<<((size_t)E_ * H_ / 4 + 255) / 256, 256, 0, stream>>>(W_h2o, Wh2obf, (long long)E_ * H_);
    conv_bf16<<<((size_t)V_ * E_ / 4 + 255) / 256, 256, 0, stream>>>(W_o2p, Wo2pbf, (long long)V_ * E_);

    // ---- batched tail (bf16 MFMA) ----
    mfma_nt<1><<<dim3(E_ / 128, MP_ / 128), 256, 0, stream>>>(h2ring + (size_t)B_ * H_, Wh2obf, b_h2o,
                                                              lg_bf, nullptr, E_, H_, 0);
    mfma_nt<2><<<dim3(V_ / 128, MP_ / 128), 256, 0, stream>>>(lg_bf, Wo2pbf, b_o2p,
                                                              nullptr, pp, V_, E_, NT2);
    row_loss_k<<<R_, 64, 0, stream>>>(pp, lg_bf, Wo2pbf, b_o2p, y, rl);
    sum_k<<<1, 256, 0, stream>>>(rl, out);
}

// Round 6
// 8933.022 us; speedup vs baseline: 3.7931x; 1.2801x over previous
//
#include <hip/hip_runtime.h>
#include <math.h>

#define T_ 100
#define B_ 64
#define S_ 128
#define E_ 512
#define H_ 1024
#define C_ 512
#define V_ 32000
#define TS_ 99            // T-1 steps
#define R_ (TS_ * B_)     // 6336 rows
#define MP_ 6400          // rows padded to multiple of 128 for MFMA
#define NT2 250           // vocab n-tiles of 128
#define NBLK 64           // persistent-kernel grid size

typedef unsigned short ushort_t;
typedef __attribute__((ext_vector_type(8))) short short8;
typedef __attribute__((ext_vector_type(4))) float f32x4;

__device__ __forceinline__ float sigm_(float x) { return 1.0f / (1.0f + __expf(-x)); }
__device__ __forceinline__ float tanh_(float x) { float e = __expf(2.0f * x); return 1.0f - 2.0f / (e + 1.0f); }
__device__ __forceinline__ ushort_t f2bf(float f) {
    unsigned u = __float_as_uint(f);
    unsigned r = (u + 0x7FFF + ((u >> 16) & 1)) >> 16;
    return (ushort_t)r;
}
__device__ __forceinline__ float bf2f(ushort_t u) { return __uint_as_float(((unsigned)u) << 16); }

__device__ __forceinline__ float wred(float v) {
    #pragma unroll
    for (int o = 32; o; o >>= 1) v += __shfl_down(v, o);
    return v;
}
__device__ __forceinline__ float wmax(float v) {
    #pragma unroll
    for (int o = 32; o; o >>= 1) v = fmaxf(v, __shfl_down(v, o));
    return v;
}

// Distributed grid barrier, contention-free (r5's 27us/barrier was single-line
// RMW convoy: 64 serialized arrivals + 63 spinners queueing on one line).
// Here every control word is private to one block (128-B spacing):
//  - worker b: sc1-store k+1 -> arr[b]; RMW-poll its OWN rel[b]
//  - master (block 0): 63 lanes RMW-poll the 63 arr slots IN PARALLEL
//    (distinct lines -> concurrent service), then store k+1 to 63 rel slots.
// ~2 coherence round trips total; no cache-maintenance ops anywhere, so
// weights/ctx stay L2-resident. Data plane: sc1 stores to virgin ring
// addresses (proven correct rounds 3-5).
__device__ __forceinline__ void gbar(int* arr, int* rel, int k) {
    __syncthreads();   // all waves drain vmcnt -> this block's sc1 stores are coherent
    const int bid = blockIdx.x, tid = threadIdx.x;
    if (bid == 0) {
        if (tid > 0 && tid < 64) {
            int* a = arr + tid * 32;
            while (__hip_atomic_fetch_add(a, 0, __ATOMIC_RELAXED, __HIP_MEMORY_SCOPE_AGENT) < k + 1)
                __builtin_amdgcn_s_sleep(1);
        }
        __syncthreads();
        if (tid > 0 && tid < 64)
            __hip_atomic_store(rel + tid * 32, k + 1, __ATOMIC_RELAXED, __HIP_MEMORY_SCOPE_AGENT);
        __syncthreads();
    } else {
        if (tid == 0) {
            __builtin_amdgcn_s_waitcnt(0);
            __hip_atomic_store(arr + bid * 32, k + 1, __ATOMIC_RELAXED, __HIP_MEMORY_SCOPE_AGENT);
            while (__hip_atomic_fetch_add(rel + bid * 32, 0, __ATOMIC_RELAXED, __HIP_MEMORY_SCOPE_AGENT) < k + 1)
                __builtin_amdgcn_s_sleep(1);
        }
        __syncthreads();
    }
}

// ---------------------------------------------------------------------------
// Fused GRU phase. 64 blocks, block owns 16 j (48 packed rows).
// Wp packed [3072][1536] bf16: row c=3*jj+g = [Wih[g*1024+jj][0:512] | Whh[g*1024+jj][0:1024]].
// Outputs h (bf16) via sc1 stores into a virgin ring slot.
// ---------------------------------------------------------------------------
__device__ __forceinline__ void gru_phase(
    int tid, int c0,
    const ushort_t* __restrict__ ax,   // [64][512] bf16
    const ushort_t* __restrict__ ah,   // [64][1024] bf16
    const ushort_t* __restrict__ Wp,
    const float* __restrict__ bi, const float* __restrict__ bh,
    const ushort_t* __restrict__ hpbf, // [64][1024] bf16 prev h
    ushort_t* __restrict__ hout,       // [64][1024] bf16 ring slot (sc1 stores)
    float* __restrict__ sm)            // 12288 floats LDS
{
    const int w = tid >> 6, lane = tid & 63, quad = lane >> 4, l16 = lane & 15;
    f32x4 accX[12] = {};
    f32x4 accH[12] = {};
    const int kc0 = w * 12;   // 48 kc slices: kc<16 -> x (K=512), kc>=16 -> h (K=1024)
    #pragma unroll
    for (int i = 0; i < 12; ++i) {
        const int kc = kc0 + i;
        const int kw = kc * 32 + quad * 8;
        short8 bfr[3];
        #pragma unroll
        for (int ct = 0; ct < 3; ++ct)
            bfr[ct] = *(const short8*)(Wp + (size_t)(c0 + ct * 16 + l16) * 1536 + kw);
        short8 af[4];
        if (kc < 16) {
            #pragma unroll
            for (int mt = 0; mt < 4; ++mt)
                af[mt] = *(const short8*)(ax + (size_t)(mt * 16 + l16) * 512 + kw);
            #pragma unroll
            for (int mt = 0; mt < 4; ++mt)
                #pragma unroll
                for (int ct = 0; ct < 3; ++ct)
                    accX[mt * 3 + ct] = __builtin_amdgcn_mfma_f32_16x16x32_bf16(af[mt], bfr[ct], accX[mt * 3 + ct], 0, 0, 0);
        } else {
            const int ko = (kc - 16) * 32 + quad * 8;
            #pragma unroll
            for (int mt = 0; mt < 4; ++mt)
                af[mt] = *(const short8*)(ah + (size_t)(mt * 16 + l16) * 1024 + ko);
            #pragma unroll
            for (int mt = 0; mt < 4; ++mt)
                #pragma unroll
                for (int ct = 0; ct < 3; ++ct)
                    accH[mt * 3 + ct] = __builtin_amdgcn_mfma_f32_16x16x32_bf16(af[mt], bfr[ct], accH[mt * 3 + ct], 0, 0, 0);
        }
    }
    // LDS reduce round 1: X partials
    #pragma unroll
    for (int p = 0; p < 12; ++p)
        #pragma unroll
        for (int r = 0; r < 4; ++r)
            sm[w * 3072 + p * 256 + (quad * 4 + r) * 16 + l16] = accX[p][r];
    __syncthreads();
    float Xg[2][2][3], Hg[2][2][3];
    #pragma unroll
    for (int q = 0; q < 2; ++q) {
        int o = q * 256 + tid, b = o >> 3, jp = o & 7;
        int mt3 = (b >> 4) * 3, e0 = (b & 15) * 16;
        #pragma unroll
        for (int jj = 0; jj < 2; ++jj)
            #pragma unroll
            for (int g = 0; g < 3; ++g) {
                int c = (jp * 2 + jj) * 3 + g;
                int p = mt3 + (c >> 4), e = e0 + (c & 15);
                Xg[q][jj][g] = sm[p * 256 + e] + sm[3072 + p * 256 + e]
                             + sm[6144 + p * 256 + e] + sm[9216 + p * 256 + e];
            }
    }
    __syncthreads();
    // LDS reduce round 2: H partials
    #pragma unroll
    for (int p = 0; p < 12; ++p)
        #pragma unroll
        for (int r = 0; r < 4; ++r)
            sm[w * 3072 + p * 256 + (quad * 4 + r) * 16 + l16] = accH[p][r];
    __syncthreads();
    #pragma unroll
    for (int q = 0; q < 2; ++q) {
        int o = q * 256 + tid, b = o >> 3, jp = o & 7;
        int mt3 = (b >> 4) * 3, e0 = (b & 15) * 16;
        #pragma unroll
        for (int jj = 0; jj < 2; ++jj)
            #pragma unroll
            for (int g = 0; g < 3; ++g) {
                int c = (jp * 2 + jj) * 3 + g;
                int p = mt3 + (c >> 4), e = e0 + (c & 15);
                Hg[q][jj][g] = sm[p * 256 + e] + sm[3072 + p * 256 + e]
                             + sm[6144 + p * 256 + e] + sm[9216 + p * 256 + e];
            }
    }
    const int j0 = c0 / 3;
    #pragma unroll
    for (int q = 0; q < 2; ++q) {
        int o = q * 256 + tid, b = o >> 3, jp = o & 7;
        unsigned pack = 0;
        #pragma unroll
        for (int jj = 0; jj < 2; ++jj) {
            int j = j0 + jp * 2 + jj;
            float r = sigm_(Xg[q][jj][0] + Hg[q][jj][0] + bi[j] + bh[j]);
            float z = sigm_(Xg[q][jj][1] + Hg[q][jj][1] + bi[1024 + j] + bh[1024 + j]);
            float n = tanh_(Xg[q][jj][2] + bi[2048 + j] + r * (Hg[q][jj][2] + bh[2048 + j]));
            float hp = bf2f(hpbf[(size_t)b * 1024 + j]);
            float h = (1.0f - z) * n + z * hp;
            pack |= ((unsigned)f2bf(h)) << (16 * jj);
        }
        __hip_atomic_store((unsigned*)(hout + (size_t)b * 1024) + (j0 >> 1) + jp, pack,
                           __ATOMIC_RELAXED, __HIP_MEMORY_SCOPE_AGENT);
    }
}

// ---------------------------------------------------------------------------
// Persistent decode loop: 64 blocks x 256 threads, 4 phases + 4 barriers/step.
// ---------------------------------------------------------------------------
__global__ __launch_bounds__(256, 1) void decode_persist(
    const ushort_t* __restrict__ xembbf,   // [R_][512]
    const ushort_t* __restrict__ ctxpbf,   // [S*B][512]
    const ushort_t* __restrict__ ctxbf,    // [S*B][512]
    const ushort_t* __restrict__ Wp0,
    const ushort_t* __restrict__ Wp1,
    const ushort_t* __restrict__ Wh2cbf,   // [512 c][1024 k] bf16 row-major
    const float* __restrict__ bi0, const float* __restrict__ bh0,
    const float* __restrict__ bi1, const float* __restrict__ bh1,
    const float* __restrict__ wmlp,
    ushort_t* __restrict__ h1ring,         // [99][64][1024]
    ushort_t* __restrict__ zring,          // [99][64][512]
    ushort_t* __restrict__ hidring,        // [99][64][512]
    ushort_t* __restrict__ h2ring,         // [100 slots][64][1024]; slot0 = zeros
    int* arr, int* rel)
{
    __shared__ float sm[12288];   // 48 KB, reused by all phases
    const int bid = blockIdx.x, tid = threadIdx.x;
    const int w = tid >> 6, lane = tid & 63;
    const int quad = lane >> 4, l16 = lane & 15;
    int bk = 0;
    for (int t = 0; t < TS_; ++t) {
        const ushort_t* h2prev = h2ring + (size_t)t * 65536;
        ushort_t* h1slot  = h1ring + (size_t)t * 65536;
        ushort_t* zslot   = zring + (size_t)t * 32768;
        ushort_t* hidslot = hidring + (size_t)t * 32768;
        // ---- P1: GRU0 -> h1 ----
        gru_phase(tid, bid * 48, xembbf + (size_t)t * 32768, h2prev, Wp0,
                  bi0, bh0, h2prev, h1slot, sm);
        gbar(arr, rel, bk++);
        // ---- P2: hid = h1 @ W_h2c^T (32 blocks, MFMA) ----
        if (bid < 32) {
            const int c0 = bid * 16;
            f32x4 acc[4] = {};
            #pragma unroll
            for (int i = 0; i < 8; ++i) {
                const int ko = (w * 8 + i) * 32 + quad * 8;
                short8 bfr = *(const short8*)(Wh2cbf + (size_t)(c0 + l16) * 1024 + ko);
                #pragma unroll
                for (int mt = 0; mt < 4; ++mt) {
                    short8 af = *(const short8*)(h1slot + (size_t)(mt * 16 + l16) * 1024 + ko);
                    acc[mt] = __builtin_amdgcn_mfma_f32_16x16x32_bf16(af, bfr, acc[mt], 0, 0, 0);
                }
            }
            #pragma unroll
            for (int mt = 0; mt < 4; ++mt)
                #pragma unroll
                for (int r = 0; r < 4; ++r)
                    sm[w * 1024 + mt * 256 + (quad * 4 + r) * 16 + l16] = acc[mt][r];
            __syncthreads();
            #pragma unroll
            for (int mt = 0; mt < 4; ++mt) {
                float v = sm[mt * 256 + tid] + sm[1024 + mt * 256 + tid]
                        + sm[2048 + mt * 256 + tid] + sm[3072 + mt * 256 + tid];
                int b = mt * 16 + (tid >> 4), c = c0 + (tid & 15);
                __hip_atomic_store(hidslot + (size_t)b * 512 + c, f2bf(v),
                                   __ATOMIC_RELAXED, __HIP_MEMORY_SCOPE_AGENT);
            }
        }
        gbar(arr, rel, bk++);
        // ---- P3: attention -> z (64 blocks, one per b) ----
        {
            const int b = bid;
            float* hd = sm;             // 512
            float* wm = sm + 512;       // 512
            float* sc = sm + 1024;      // 128
            const ushort_t* hidrow = hidslot + (size_t)b * 512;
            for (int k2 = tid; k2 < 512; k2 += 256) { hd[k2] = bf2f(hidrow[k2]); wm[k2] = wmlp[k2]; }
            __syncthreads();
            for (int s = w * 32; s < w * 32 + 32; ++s) {
                const short8 v8 = *(const short8*)(ctxpbf + ((size_t)s * 64 + b) * 512 + lane * 8);
                float acc = 0;
                #pragma unroll
                for (int e = 0; e < 8; ++e) {
                    int c = lane * 8 + e;
                    acc += tanh_(bf2f((ushort_t)v8[e]) + hd[c]) * wm[c];
                }
                acc = wred(acc);
                if (lane == 0) sc[s] = acc;
            }
            __syncthreads();
            if (w == 0) {
                float s0 = sc[lane], s1 = sc[lane + 64];
                float m = fmaxf(s0, s1);
                m = wmax(m); m = __shfl(m, 0);
                float e0 = __expf(s0 - m), e1 = __expf(s1 - m);
                float ssum = wred(e0 + e1); ssum = __shfl(ssum, 0);
                float inv = 1.0f / ssum;
                sc[lane] = e0 * inv; sc[lane + 64] = e1 * inv;
            }
            __syncthreads();
            {
                const int c2 = tid * 2;
                float a0 = 0, a1 = 0;
                #pragma unroll 8
                for (int s = 0; s < 128; ++s) {
                    float al = sc[s];
                    ushort2 u = *(const ushort2*)(ctxbf + ((size_t)s * 64 + b) * 512 + c2);
                    a0 += al * bf2f(u.x); a1 += al * bf2f(u.y);
                }
                unsigned pack = (unsigned)f2bf(a0) | (((unsigned)f2bf(a1)) << 16);
                __hip_atomic_store((unsigned*)zslot + b * 256 + tid, pack,
                                   __ATOMIC_RELAXED, __HIP_MEMORY_SCOPE_AGENT);
            }
        }
        gbar(arr, rel, bk++);
        // ---- P4: GRU1 -> h2 (slot t+1) ----
        gru_phase(tid, bid * 48, zslot, h1slot, Wp1,
                  bi1, bh1, h1slot, h2ring + (size_t)(t + 1) * 65536, sm);
        gbar(arr, rel, bk++);
    }
}

// ---------------------------------------------------------------------------
// fp32-in bf16-out tiled GEMM-NT for ctx_p precompute.
// ---------------------------------------------------------------------------
__global__ __launch_bounds__(256) void gemm_nt_bf(const float* __restrict__ A,
                                                  const float* __restrict__ Bw,
                                                  ushort_t* __restrict__ Cbf,
                                                  int N, int K) {
    __shared__ __align__(16) float As[16][68];
    __shared__ __align__(16) float Bs[16][68];
    const int tid = threadIdx.x;
    const int m0 = blockIdx.y * 64, n0 = blockIdx.x * 64;
    const int tx = tid & 15, ty = tid >> 4;
    const int lr = tid >> 2, lk = (tid & 3) << 2;
    float acc[4][4] = {};
    const float* Ap = A + (size_t)(m0 + lr) * K + lk;
    const float* Bp = Bw + (size_t)(n0 + lr) * K + lk;
    for (int kt = 0; kt < K; kt += 16) {
        float4 av = *(const float4*)(Ap + kt);
        float4 bv = *(const float4*)(Bp + kt);
        __syncthreads();
        As[lk + 0][lr] = av.x; As[lk + 1][lr] = av.y; As[lk + 2][lr] = av.z; As[lk + 3][lr] = av.w;
        Bs[lk + 0][lr] = bv.x; Bs[lk + 1][lr] = bv.y; Bs[lk + 2][lr] = bv.z; Bs[lk + 3][lr] = bv.w;
        __syncthreads();
        #pragma unroll
        for (int kk = 0; kk < 16; ++kk) {
            float4 a = *(const float4*)&As[kk][ty << 2];
            float4 b = *(const float4*)&Bs[kk][tx << 2];
            float ar[4] = {a.x, a.y, a.z, a.w};
            float br[4] = {b.x, b.y, b.z, b.w};
            #pragma unroll
            for (int i = 0; i < 4; ++i)
                #pragma unroll
                for (int j = 0; j < 4; ++j) acc[i][j] = fmaf(ar[i], br[j], acc[i][j]);
        }
    }
    #pragma unroll
    for (int i = 0; i < 4; ++i)
        #pragma unroll
        for (int j = 0; j < 4; ++j)
            Cbf[(size_t)(m0 + (ty << 2) + i) * N + n0 + (tx << 2) + j] = f2bf(acc[i][j]);
}

// ---------------------------------------------------------------------------
// bf16 MFMA GEMM-NT 128x128 tail. EPI==1: tanh(acc+bias)->bf16. EPI==2: LSE partials.
// ---------------------------------------------------------------------------
template <int EPI>
__global__ __launch_bounds__(256) void mfma_nt(const ushort_t* __restrict__ A,
                                               const ushort_t* __restrict__ Bw,
                                               const float* __restrict__ bias,
                                               ushort_t* __restrict__ Cbf,
                                               float2* __restrict__ pp,
                                               int N, int K, int NT) {
    __shared__ ushort_t As[128 * 72];
    __shared__ ushort_t Bs[128 * 72];
    __shared__ float smM[2][128], smS[2][128];
    const int tid = threadIdx.x;
    const int m0 = blockIdx.y * 128, n0 = blockIdx.x * 128;
    const int w = tid >> 6, lane = tid & 63;
    const int quad = lane >> 4, l16 = lane & 15;
    f32x4 acc[4][4] = {};
    for (int kc = 0; kc < K; kc += 64) {
        __syncthreads();
        #pragma unroll
        for (int i = 0; i < 4; ++i) {
            int cid = i * 256 + tid;
            int row = cid >> 3, c8 = cid & 7;
            uint4 va = *(const uint4*)(A + (size_t)(m0 + row) * K + kc + c8 * 8);
            *(uint4*)(&As[row * 72 + c8 * 8]) = va;
            uint4 vb = *(const uint4*)(Bw + (size_t)(n0 + row) * K + kc + c8 * 8);
            *(uint4*)(&Bs[row * 72 + c8 * 8]) = vb;
        }
        __syncthreads();
        #pragma unroll
        for (int ks = 0; ks < 2; ++ks) {
            short8 af[4], bfr[4];
            #pragma unroll
            for (int i = 0; i < 4; ++i)
                af[i] = *(const short8*)(&As[((w >> 1) * 64 + i * 16 + l16) * 72 + ks * 32 + quad * 8]);
            #pragma unroll
            for (int j = 0; j < 4; ++j)
                bfr[j] = *(const short8*)(&Bs[((w & 1) * 64 + j * 16 + l16) * 72 + ks * 32 + quad * 8]);
            #pragma unroll
            for (int i = 0; i < 4; ++i)
                #pragma unroll
                for (int j = 0; j < 4; ++j)
                    acc[i][j] = __builtin_amdgcn_mfma_f32_16x16x32_bf16(af[i], bfr[j], acc[i][j], 0, 0, 0);
        }
    }
    const int colbase = n0 + (w & 1) * 64;
    const int rowbase = m0 + (w >> 1) * 64;
    if (EPI == 1) {
        #pragma unroll
        for (int j = 0; j < 4; ++j) {
            int col = colbase + j * 16 + l16;
            float bv = bias[col];
            #pragma unroll
            for (int i = 0; i < 4; ++i)
                #pragma unroll
                for (int r = 0; r < 4; ++r) {
                    int row = rowbase + i * 16 + quad * 4 + r;
                    Cbf[(size_t)row * N + col] = f2bf(tanh_(acc[i][j][r] + bv));
                }
        }
    } else {
        float bv[4];
        #pragma unroll
        for (int j = 0; j < 4; ++j) bv[j] = bias[colbase + j * 16 + l16];
        #pragma unroll
        for (int i = 0; i < 4; ++i) {
            #pragma unroll
            for (int r = 0; r < 4; ++r) {
                float x0 = acc[i][0][r] + bv[0], x1 = acc[i][1][r] + bv[1];
                float x2 = acc[i][2][r] + bv[2], x3 = acc[i][3][r] + bv[3];
                float mx = fmaxf(fmaxf(x0, x1), fmaxf(x2, x3));
                #pragma unroll
                for (int o = 1; o < 16; o <<= 1) mx = fmaxf(mx, __shfl_xor(mx, o));
                float s = __expf(x0 - mx) + __expf(x1 - mx) + __expf(x2 - mx) + __expf(x3 - mx);
                #pragma unroll
                for (int o = 1; o < 16; o <<= 1) s += __shfl_xor(s, o);
                if (l16 == 0) {
                    int rr = (w >> 1) * 64 + i * 16 + quad * 4 + r;
                    smM[w & 1][rr] = mx;
                    smS[w & 1][rr] = s;
                }
            }
        }
        __syncthreads();
        if (tid < 128) {
            float ma = smM[0][tid], mb = smM[1][tid];
            float M = fmaxf(ma, mb);
            float S = smS[0][tid] * __expf(ma - M) + smS[1][tid] * __expf(mb - M);
            pp[(size_t)(m0 + tid) * NT + blockIdx.x] = make_float2(M, S);
        }
    }
}

__global__ __launch_bounds__(256) void conv_bf16(const float* __restrict__ src,
                                                 ushort_t* __restrict__ dst,
                                                 long long n) {
    long long base = ((long long)blockIdx.x * 256 + threadIdx.x) * 4;
    if (base >= n) return;
    float4 v = *(const float4*)(src + base);
    *(ushort2*)(dst + base) = make_ushort2(f2bf(v.x), f2bf(v.y));
    *(ushort2*)(dst + base + 2) = make_ushort2(f2bf(v.z), f2bf(v.w));
}

// pack GRU weights: row c = 3*jj+g -> [Wih[g*1024+jj][0:512] | Whh[g*1024+jj][0:1024]], bf16.
__global__ __launch_bounds__(256) void pack_gru(const float* __restrict__ Wih,
                                                const float* __restrict__ Whh,
                                                ushort_t* __restrict__ Wp) {
    const int c = blockIdx.x;           // 0..3071
    const int jj = c / 3, g = c % 3;
    const int src = g * 1024 + jj;
    ushort_t* dst = Wp + (size_t)c * 1536;
    for (int k = threadIdx.x; k < 512; k += 256) dst[k] = f2bf(Wih[(size_t)src * 512 + k]);
    for (int k = threadIdx.x; k < 1024; k += 256) dst[512 + k] = f2bf(Whh[(size_t)src * 1024 + k]);
}

__global__ __launch_bounds__(128) void gather_emb_bf(const float* __restrict__ emb,
                                                     const int* __restrict__ y,
                                                     ushort_t* __restrict__ xall) {
    const int r = blockIdx.x;
    const int tok = y[r];
    const float* src = emb + (size_t)tok * 512;
    ushort_t* dst = xall + (size_t)r * 512;
    int k = threadIdx.x * 4;
    float4 v = *(const float4*)(src + k);
    *(ushort2*)(dst + k) = make_ushort2(f2bf(v.x), f2bf(v.y));
    *(ushort2*)(dst + k + 2) = make_ushort2(f2bf(v.z), f2bf(v.w));
}

__global__ __launch_bounds__(64) void row_loss_k(const float2* __restrict__ pp,
                                                 const ushort_t* __restrict__ lg,
                                                 const ushort_t* __restrict__ Wvbf,
                                                 const float* __restrict__ bv,
                                                 const int* __restrict__ y,
                                                 float* __restrict__ rl) {
    const int r = blockIdx.x;
    const int lane = threadIdx.x;
    const int t = r / B_, b = r % B_;
    const int tgt = y[(t + 1) * B_ + b];
    float m = -1e30f;
    for (int i = lane; i < NT2; i += 64) m = fmaxf(m, pp[(size_t)r * NT2 + i].x);
    m = wmax(m); m = __shfl(m, 0);
    float s = 0;
    for (int i = lane; i < NT2; i += 64) {
        float2 p = pp[(size_t)r * NT2 + i];
        s += p.y * __expf(p.x - m);
    }
    s = wred(s);
    float d = 0;
    for (int k = lane; k < E_; k += 64)
        d += bf2f(lg[(size_t)r * E_ + k]) * bf2f(Wvbf[(size_t)tgt * E_ + k]);
    d = wred(d);
    if (lane == 0) {
        float lse = m + logf(s);
        rl[r] = (tgt != 0) ? (lse - (d + bv[tgt])) : 0.0f;
    }
}

__global__ __launch_bounds__(256) void sum_k(const float* __restrict__ rl, float* __restrict__ out) {
    float s = 0;
    for (int i = threadIdx.x; i < R_; i += 256) s += rl[i];
    __shared__ float red[4];
    s = wred(s);
    if ((threadIdx.x & 63) == 0) red[threadIdx.x >> 6] = s;
    __syncthreads();
    if (threadIdx.x == 0) out[0] = red[0] + red[1] + red[2] + red[3];
}

extern "C" void kernel_launch(void* const* d_in, const int* in_sizes, int n_in,
                              void* d_out, int out_size, void* d_ws, size_t ws_size,
                              hipStream_t stream) {
    const int*   y     = (const int*)d_in[0];
    const float* ctx   = (const float*)d_in[1];
    const float* emb   = (const float*)d_in[2];
    const float* W_ih0 = (const float*)d_in[3];
    const float* W_hh0 = (const float*)d_in[4];
    const float* b_ih0 = (const float*)d_in[5];
    const float* b_hh0 = (const float*)d_in[6];
    const float* W_ih1 = (const float*)d_in[7];
    const float* W_hh1 = (const float*)d_in[8];
    const float* b_ih1 = (const float*)d_in[9];
    const float* b_hh1 = (const float*)d_in[10];
    const float* W_c2c = (const float*)d_in[11];
    const float* W_h2c = (const float*)d_in[12];
    const float* w_mlp = (const float*)d_in[13];
    const float* W_h2o = (const float*)d_in[14];
    const float* b_h2o = (const float*)d_in[15];
    const float* W_o2p = (const float*)d_in[16];
    const float* b_o2p = (const float*)d_in[17];
    float* out = (float*)d_out;

    // ---- workspace layout: loop-phase view and tail-phase view share region A ----
    char* base = (char*)d_ws;
    int* arr = (int*)base;                         // 64 slots x 128 B = 8 KB
    int* rel = (int*)(base + 8192);                // 64 slots x 128 B = 8 KB
    char* regA = base + 16384;
    // loop view of region A:
    ushort_t* ctxpbf  = (ushort_t*)(regA);                       //  8,388,608
    ushort_t* ctxbf   = (ushort_t*)(regA + 8388608);             //  8,388,608
    ushort_t* xembbf  = (ushort_t*)(regA + 16777216);            //  6,488,064
    ushort_t* Wp0     = (ushort_t*)(regA + 23265280);            //  9,437,184
    ushort_t* Wp1     = (ushort_t*)(regA + 32702464);            //  9,437,184
    ushort_t* Wh2cbf  = (ushort_t*)(regA + 42139648);            //  1,048,576
    ushort_t* h1ring  = (ushort_t*)(regA + 43188224);            // 12,976,128
    ushort_t* zring   = (ushort_t*)(regA + 56164352);            //  6,488,064
    ushort_t* hidring = (ushort_t*)(regA + 62652416);            //  6,488,064 -> end 69,140,480
    // tail view of region A (live only after decode_persist):
    ushort_t* Wo2pbf  = (ushort_t*)(regA);                       // 32,768,000
    ushort_t* Wh2obf  = (ushort_t*)(regA + 32768000);            //  1,048,576
    ushort_t* lg_bf   = (ushort_t*)(regA + 33816576);            //  6,553,600
    float2*   pp      = (float2*)(regA + 40370176);              // 12,800,000
    float*    rl      = (float*)(regA + 53170176);               //     25,344
    // region B (live across both phases):
    ushort_t* h2ring  = (ushort_t*)(regA + 69140480);            // 13,238,272 (6464 rows x 1024)

    // ---- init ----
    hipMemsetAsync(arr, 0, 16384, stream);
    hipMemsetAsync(h2ring, 0, (size_t)B_ * H_ * 2, stream);                       // slot 0 = h_init
    hipMemsetAsync(h2ring + (size_t)(B_ + R_) * H_, 0, (size_t)(MP_ - R_) * H_ * 2, stream); // pad rows

    // ---- precompute (loop-phase buffers) ----
    gemm_nt_bf<<<dim3(C_ / 64, (S_ * B_) / 64), 256, 0, stream>>>(ctx, W_c2c, ctxpbf, C_, C_);
    conv_bf16<<<((size_t)S_ * B_ * C_ / 4 + 255) / 256, 256, 0, stream>>>(ctx, ctxbf, (long long)S_ * B_ * C_);
    gather_emb_bf<<<R_, 128, 0, stream>>>(emb, y, xembbf);
    pack_gru<<<3072, 256, 0, stream>>>(W_ih0, W_hh0, Wp0);
    pack_gru<<<3072, 256, 0, stream>>>(W_ih1, W_hh1, Wp1);
    conv_bf16<<<((size_t)C_ * H_ / 4 + 255) / 256, 256, 0, stream>>>(W_h2c, Wh2cbf, (long long)C_ * H_);

    // ---- persistent sequential decode loop ----
    decode_persist<<<NBLK, 256, 0, stream>>>(xembbf, ctxpbf, ctxbf, Wp0, Wp1, Wh2cbf,
                                             b_ih0, b_hh0, b_ih1, b_hh1, w_mlp,
                                             h1ring, zring, hidring, h2ring, arr, rel);

    // ---- tail-phase conversions (overlay loop buffers, safe after decode) ----
    conv_bf16<<<((size_t)E_ * H_ / 4 + 255) / 256, 256, 0, stream>>>(W_h2o, Wh2obf, (long long)E_ * H_);
    conv_bf16<<<((size_t)V_ * E_ / 4 + 255) / 256, 256, 0, stream>>>(W_o2p, Wo2pbf, (long long)V_ * E_);

    // ---- batched tail (bf16 MFMA) ----
    mfma_nt<1><<<dim3(E_ / 128, MP_ / 128), 256, 0, stream>>>(h2ring + (size_t)B_ * H_, Wh2obf, b_h2o,
                                                              lg_bf, nullptr, E_, H_, 0);
    mfma_nt<2><<<dim3(V_ / 128, MP_ / 128), 256, 0, stream>>>(lg_bf, Wo2pbf, b_o2p,
                                                              nullptr, pp, V_, E_, NT2);
    row_loss_k<<<R_, 64, 0, stream>>>(pp, lg_bf, Wo2pbf, b_o2p, y, rl);
    sum_k<<<1, 256, 0, stream>>>(rl, out);
}